// Round 4
// baseline (442.576 us; speedup 1.0000x reference)
//
#include <hip/hip_runtime.h>

// B=4, T=1024, C=16, D=256, P=4096.  Float tensors fp32; x_mask u8; pos i32.
// ws: q[bc][t][d] bf16 32MB | k[bc][t][d] bf16 32MB | vt[bc][d][t] bf16 32MB
//     | wb[3][256][256] bf16 384KB | mbg[64][1024] f32 256KB

typedef __attribute__((ext_vector_type(8))) short short8_t;
typedef __attribute__((ext_vector_type(4))) short short4_t;
typedef __attribute__((ext_vector_type(8))) float float8_t;
typedef __attribute__((ext_vector_type(4))) float float4_t;
typedef __attribute__((ext_vector_type(2))) float float2_t;

__device__ __forceinline__ float b2f(short s) {
    union { unsigned int u; float f; } x;
    x.u = ((unsigned int)(unsigned short)s) << 16;
    return x.f;
}
__device__ __forceinline__ short f2bt(float f) {   // truncate: ample headroom here
    union { float f; unsigned int u; } x; x.f = f;
    return (short)(x.u >> 16);
}
__device__ __forceinline__ void b2f8(const short8_t v, float* f) {
#pragma unroll
    for (int i = 0; i < 8; i++) f[i] = b2f(v[i]);
}

// async global->LDS, 16B per lane, dest = wave-uniform base + lane*16
__device__ __forceinline__ void stage16(const short* g, short* l) {
    __builtin_amdgcn_global_load_lds(
        (const __attribute__((address_space(1))) unsigned int*)g,
        (__attribute__((address_space(3))) unsigned int*)l, 16, 0, 0);
}

// ---------------------------------------------------------------------------
// Kernel 0: weights fp32->bf16 + mask-bias table. 448 blocks x 256.
// ---------------------------------------------------------------------------
__global__ __launch_bounds__(256) void prep_kernel(
    const float* __restrict__ wq, const float* __restrict__ wk,
    const float* __restrict__ wv, const unsigned char* __restrict__ xmask,
    short* __restrict__ wb, float* __restrict__ mbg)
{
    if (blockIdx.x < 192) {
        int idx = blockIdx.x * 256 + threadIdx.x;
        int mat = idx >> 14, off = idx & 16383;
        const float* src = (mat == 0) ? wq : ((mat == 1) ? wk : wv);
        float4_t v = *(const float4_t*)(src + (long)off * 4);
        short4_t o;
#pragma unroll
        for (int j = 0; j < 4; j++) o[j] = f2bt(v[j]);
        *(short4_t*)(wb + (long)idx * 4) = o;
    } else {
        int idx = (blockIdx.x - 192) * 256 + threadIdx.x;   // 0..65535
        int bc = idx >> 10, t = idx & 1023;
        int b = bc >> 4, c = bc & 15;
        mbg[idx] = xmask[((long)b * 1024 + t) * 16 + c] ? -1e30f : 0.0f;
    }
}

// ---------------------------------------------------------------------------
// Kernel 1: MFMA QKV projection + rotary (unchanged).
// ---------------------------------------------------------------------------
__global__ __launch_bounds__(256) void qkv_mfma_kernel(
    const float* __restrict__ x, const int* __restrict__ pos,
    const float* __restrict__ pe, const short* __restrict__ wb,
    const float* __restrict__ bq, const float* __restrict__ bk,
    const float* __restrict__ bv,
    short* __restrict__ qo, short* __restrict__ ko, short* __restrict__ vt)
{
    __shared__ __align__(16) short xs[64 * 264];
    __shared__ __align__(16) short ys[18432];
    __shared__ int posb[64];

    const int tid = threadIdx.x;
    const int lane = tid & 63;
    const int wid = tid >> 6;
    const int bc = blockIdx.x >> 4;
    const int t0 = (blockIdx.x & 15) * 64;
    const int b = bc >> 4, c = bc & 15;
    const int row = lane & 15, quad = lane >> 4;
    const int odd = lane & 1;
    const int n0 = wid * 64;
    const long kvbase = (long)bc * 262144;

#pragma unroll
    for (int j = 0; j < 8; j++) {
        int idx = tid + j * 256;
        int r = idx >> 5, c8 = idx & 31;
        const float* xp = x + (((long)b * 1024 + t0 + r) * 16 + c) * 256 + c8 * 8;
        float4_t a = *(const float4_t*)xp;
        float4_t d = *(const float4_t*)(xp + 4);
        short8_t o;
        o[0] = f2bt(a.x); o[1] = f2bt(a.y); o[2] = f2bt(a.z); o[3] = f2bt(a.w);
        o[4] = f2bt(d.x); o[5] = f2bt(d.y); o[6] = f2bt(d.z); o[7] = f2bt(d.w);
        *(short8_t*)&xs[r * 264 + c8 * 8] = o;
    }
    if (tid < 64) posb[tid] = pos[((long)b * 1024 + t0 + tid) * 16 + c];
    __syncthreads();

#pragma unroll 1
    for (int mat = 0; mat < 3; mat++) {
        const short* W = wb + mat * 65536;
        float4_t acc[4][4];
#pragma unroll
        for (int mt = 0; mt < 4; mt++)
#pragma unroll
            for (int nt = 0; nt < 4; nt++) acc[mt][nt] = (float4_t){0.f, 0.f, 0.f, 0.f};

        short8_t Ac[4], Bc[4], An[4], Bn[4];
        auto loadA = [&](short8_t* A, int k0) {
#pragma unroll
            for (int mt = 0; mt < 4; mt++)
                A[mt] = *(const short8_t*)&xs[(mt * 16 + row) * 264 + k0 * 32 + quad * 8];
        };
        auto loadB = [&](short8_t* Bf, int k0) {
#pragma unroll
            for (int nt = 0; nt < 4; nt++)
                Bf[nt] = *(const short8_t*)(W + (n0 + nt * 16 + row) * 256 + k0 * 32 + quad * 8);
        };
        loadA(Ac, 0); loadB(Bc, 0);
#pragma unroll
        for (int k0 = 0; k0 < 8; k0++) {
            if (k0 < 7) { loadA(An, k0 + 1); loadB(Bn, k0 + 1); }
#pragma unroll
            for (int mt = 0; mt < 4; mt++)
#pragma unroll
                for (int nt = 0; nt < 4; nt++)
                    acc[mt][nt] = __builtin_amdgcn_mfma_f32_16x16x32_bf16(
                        Ac[mt], Bc[nt], acc[mt][nt], 0, 0, 0);
            if (k0 < 7) {
#pragma unroll
                for (int i = 0; i < 4; i++) { Ac[i] = An[i]; Bc[i] = Bn[i]; }
            }
        }

        const float* bias = (mat == 0) ? bq : ((mat == 1) ? bk : bv);
        float bs[4];
#pragma unroll
        for (int nt = 0; nt < 4; nt++) bs[nt] = bias[n0 + nt * 16 + row];
#pragma unroll
        for (int mt = 0; mt < 4; mt++)
#pragma unroll
            for (int nt = 0; nt < 4; nt++)
#pragma unroll
                for (int r = 0; r < 4; r++) acc[mt][nt][r] += bs[nt];

        if (mat < 2) {
#pragma unroll
            for (int mt = 0; mt < 4; mt++)
#pragma unroll
                for (int r = 0; r < 4; r++) {
                    int p = posb[mt * 16 + quad * 4 + r];
                    const float* pb = pe + (long)p * 256;
#pragma unroll
                    for (int nt = 0; nt < 4; nt++) {
                        int i = (n0 + nt * 16 + row) >> 1;
                        float2_t cs = *(const float2_t*)(pb + i * 2);
                        float v = acc[mt][nt][r];
                        float pr = __shfl_xor(v, 1);
                        acc[mt][nt][r] = v * cs.x + pr * (odd ? cs.y : -cs.y);
                    }
                }
        }

        __syncthreads();
        if (mat < 2) {
#pragma unroll
            for (int mt = 0; mt < 4; mt++)
#pragma unroll
                for (int nt = 0; nt < 4; nt++) {
                    int n = n0 + nt * 16 + row;
#pragma unroll
                    for (int r = 0; r < 4; r++)
                        ys[(mt * 16 + quad * 4 + r) * 264 + n] = f2bt(acc[mt][nt][r]);
                }
            __syncthreads();
            short* dst = ((mat == 0) ? qo : ko) + kvbase + (long)t0 * 256;
#pragma unroll
            for (int j = 0; j < 8; j++) {
                int idx = tid + j * 256;
                int r = idx >> 5, c8 = idx & 31;
                *(short8_t*)(dst + r * 256 + c8 * 8) = *(const short8_t*)&ys[r * 264 + c8 * 8];
            }
        } else {
#pragma unroll
            for (int mt = 0; mt < 4; mt++)
#pragma unroll
                for (int nt = 0; nt < 4; nt++) {
                    int n = n0 + nt * 16 + row;
                    short4_t o4;
#pragma unroll
                    for (int r = 0; r < 4; r++) o4[r] = f2bt(acc[mt][nt][r]);
                    *(short4_t*)&ys[n * 72 + mt * 16 + quad * 4] = o4;
                }
            __syncthreads();
#pragma unroll
            for (int j = 0; j < 8; j++) {
                int idx = tid + j * 256;
                int d = idx >> 3, t8 = idx & 7;
                *(short8_t*)(vt + kvbase + (long)d * 1024 + t0 + t8 * 8) =
                    *(const short8_t*)&ys[d * 72 + t8 * 8];
            }
        }
    }
}

// ---------------------------------------------------------------------------
// Kernel 2: flash attention. 512 thr (8 waves x 16 q-rows = 128 q/block),
// KV-tile 32, DOUBLE-buffered global_load_lds staging (depth-1 prefetch,
// counted vmcnt + raw s_barrier), online softmax w/ defer-max, in-reg LN.
// LDS: K 2x16KB | V 2x16KB | PT 8x1.25KB | mask 4KB = 78KB -> 2 blocks/CU
// (round-2's 110KB triple-buffer allowed only 1 block/CU = lockstep phases;
//  two independent blocks/CU let one block's softmax overlap the other's
//  MFMA).  s_setprio(1) around MFMA clusters (pays with role diversity).
// ---------------------------------------------------------------------------
__global__ __launch_bounds__(512, 4) void attn_kernel(
    const short* __restrict__ qg, const short* __restrict__ kg,
    const short* __restrict__ vt, const float* __restrict__ mbg,
    const float* __restrict__ x,
    const float* __restrict__ lsg, const float* __restrict__ lng,
    const float* __restrict__ lnb, float* __restrict__ out)
{
    __shared__ __align__(16) short lds[39936];   // 79872 B
    // shorts: Ks[buf<2] @ buf*8192 (row r*256, 16B slot s holds gcol-slot s^(r&7))
    //         Vs[buf<2] @ 16384+buf*8192 (row d*32, 4 slots, slot s = gslot^((d>>1)&3))
    //         PT[wave]  @ 32768+wid*640  (32 k-rows x stride 20 shorts)
    //         mbs f32   @ 37888 (1024 floats)

    const int tid = threadIdx.x;
    const int lane = tid & 63;
    const int wid = tid >> 6;
    // 512 blocks, 8 XCDs: chunked swizzle -> 64 consecutive bids per XCD
    const int bid = (blockIdx.x & 7) * 64 + (blockIdx.x >> 3);
    const int bc = bid >> 3;
    const int tq0 = (bid & 7) * 128;
    const int b = bc >> 4, c = bc & 15;
    const long kvbase = (long)bc * 262144;
    const int bcq = bc * 1024;
    const int row = lane & 15, quad = lane >> 4;
    float* mbsf = (float*)&lds[37888];

    auto stage = [&](int j, int buf) {
#pragma unroll
        for (int i = 0; i < 2; i++) {            // K tile: 32 rows x 512B
            int rp = (wid * 2 + i) * 2;
            int r = rp + (lane >> 5);
            int slot = lane & 31;
            const short* g = kg + kvbase + (long)(j * 32 + r) * 256 +
                             ((slot ^ (r & 7)) << 3);
            stage16(g, &lds[buf * 8192 + rp * 256]);
        }
#pragma unroll
        for (int i = 0; i < 2; i++) {            // V tile: 256 d-rows x 64B
            int db = (wid * 2 + i) * 16;
            int d = db + (lane >> 2);
            int slot = lane & 3;
            const short* g = vt + kvbase + (long)d * 1024 + j * 32 +
                             (((slot ^ ((d >> 1) & 3))) << 3);
            stage16(g, &lds[16384 + buf * 8192 + db * 32]);
        }
    };

    // ---- prologue: stage tile 0; mask row -> LDS; Q frags -> regs ----
    stage(0, 0);
#pragma unroll
    for (int i = tid; i < 1024; i += 512) mbsf[i] = mbg[bcq + i];
    short8_t aq[8];
#pragma unroll
    for (int f = 0; f < 8; f++)
        aq[f] = *(const short8_t*)(qg + kvbase +
            (long)(tq0 + wid * 16 + row) * 256 + f * 32 + quad * 8);

    float4_t oacc[16];
#pragma unroll
    for (int nt = 0; nt < 16; nt++) oacc[nt] = (float4_t){0.f, 0.f, 0.f, 0.f};
    float m[4], lsum[4];
#pragma unroll
    for (int r = 0; r < 4; r++) { m[r] = -__builtin_inff(); lsum[r] = 0.f; }

    const float scale = 0.0625f;
    const int ptw = 32768 + wid * 640 + row * 20 + quad * 4;   // PT write (k=row(+16))
    const int prd = 32768 + wid * 640 + quad * 160 + row;      // PT read (k=quad*8+jj)

    asm volatile("s_waitcnt lgkmcnt(0)" ::: "memory");   // mbs ds_writes done

#pragma unroll 1
    for (int j = 0; j < 32; j++) {
        if (j < 31) {
            stage(j + 1, (j + 1) & 1);
            asm volatile("s_waitcnt vmcnt(8)" ::: "memory");  // tile j landed
        } else {
            asm volatile("s_waitcnt vmcnt(0)" ::: "memory");
        }
        __builtin_amdgcn_s_barrier();                    // tile j staged for all waves

        const short* Kb = &lds[(j & 1) * 8192];
        const short* Vb = &lds[16384 + (j & 1) * 8192];

        // S = Q K^T  (two 16-col tiles)
        float4_t s0 = {0.f, 0.f, 0.f, 0.f}, s1 = {0.f, 0.f, 0.f, 0.f};
        __builtin_amdgcn_s_setprio(1);
#pragma unroll
        for (int f = 0; f < 8; f++) {
            short8_t k0 = *(const short8_t*)&Kb[row * 256 + (((f * 4 + quad) ^ (row & 7)) << 3)];
            short8_t k1 = *(const short8_t*)&Kb[(16 + row) * 256 + (((f * 4 + quad) ^ ((16 + row) & 7)) << 3)];
            s0 = __builtin_amdgcn_mfma_f32_16x16x32_bf16(aq[f], k0, s0, 0, 0, 0);
            s1 = __builtin_amdgcn_mfma_f32_16x16x32_bf16(aq[f], k1, s1, 0, 0, 0);
        }
        __builtin_amdgcn_s_setprio(0);
        float mb0 = mbsf[j * 32 + row], mb1 = mbsf[j * 32 + 16 + row];
        float sv[2][4], tm[4];
#pragma unroll
        for (int r = 0; r < 4; r++) {
            sv[0][r] = s0[r] * scale + mb0;
            sv[1][r] = s1[r] * scale + mb1;
            tm[r] = fmaxf(sv[0][r], sv[1][r]);
        }
#pragma unroll
        for (int r = 0; r < 4; r++)
#pragma unroll
            for (int o = 1; o < 16; o <<= 1) tm[r] = fmaxf(tm[r], __shfl_xor(tm[r], o));
        float g = fmaxf(fmaxf(tm[0] - m[0], tm[1] - m[1]),
                        fmaxf(tm[2] - m[2], tm[3] - m[3]));
        if (!__all(g <= 8.f)) {                          // rescale (rare: defer-max)
#pragma unroll
            for (int r = 0; r < 4; r++) {
                float nm = fmaxf(m[r], tm[r]);
                float fac = __expf(m[r] - nm);
                lsum[r] *= fac; m[r] = nm;
#pragma unroll
                for (int nt = 0; nt < 16; nt++) oacc[nt][r] *= fac;
            }
        }
        short4_t p4[2];
#pragma unroll
        for (int h = 0; h < 2; h++)
#pragma unroll
            for (int r = 0; r < 4; r++) {
                float p = __expf(sv[h][r] - m[r]);
                lsum[r] += p;
                p4[h][r] = f2bt(p);
            }
        *(short4_t*)&lds[ptw] = p4[0];
        *(short4_t*)&lds[ptw + 320] = p4[1];
        short8_t pa;
#pragma unroll
        for (int jj = 0; jj < 8; jj++) pa[jj] = lds[prd + jj * 20];

        // O += P V
        __builtin_amdgcn_s_setprio(1);
#pragma unroll
        for (int nt = 0; nt < 16; nt++) {
            int d = nt * 16 + row;
            short8_t vbf = *(const short8_t*)&Vb[d * 32 + ((quad ^ ((d >> 1) & 3)) << 3)];
            oacc[nt] = __builtin_amdgcn_mfma_f32_16x16x32_bf16(pa, vbf, oacc[nt], 0, 0, 0);
        }
        __builtin_amdgcn_s_setprio(0);

        asm volatile("s_waitcnt lgkmcnt(0)" ::: "memory");
        __builtin_amdgcn_s_barrier();                    // buf reads done -> reusable
    }

    // ---- epilogue: finish softmax norm; y = x + ls*o; LayerNorm; store ----
    float inv[4];
#pragma unroll
    for (int r = 0; r < 4; r++) {
        float s = lsum[r];
#pragma unroll
        for (int o = 1; o < 16; o <<= 1) s += __shfl_xor(s, o);
        int qi = tq0 + wid * 16 + quad * 4 + r;
        inv[r] = (mbsf[qi] != 0.f) ? 0.f : (1.f / s);
    }
    long xb[4];
#pragma unroll
    for (int r = 0; r < 4; r++)
        xb[r] = (((long)b * 1024 + tq0 + wid * 16 + quad * 4 + r) * 16 + c) * 256 + row;

    float s1r[4] = {0.f, 0.f, 0.f, 0.f}, s2r[4] = {0.f, 0.f, 0.f, 0.f};
#pragma unroll
    for (int nt = 0; nt < 16; nt++) {
        int d = nt * 16 + row;
        float lg = lsg[d];
#pragma unroll
        for (int r = 0; r < 4; r++) {
            float yy = x[xb[r] + nt * 16] + lg * (oacc[nt][r] * inv[r]);
            oacc[nt][r] = yy;
            s1r[r] += yy; s2r[r] += yy * yy;
        }
    }
    float mu[4], rstd[4];
#pragma unroll
    for (int r = 0; r < 4; r++) {
#pragma unroll
        for (int o = 1; o < 16; o <<= 1) {
            s1r[r] += __shfl_xor(s1r[r], o);
            s2r[r] += __shfl_xor(s2r[r], o);
        }
        mu[r] = s1r[r] * (1.f / 256.f);
        float var = s2r[r] * (1.f / 256.f) - mu[r] * mu[r];
        rstd[r] = rsqrtf(var + 1e-5f);
    }
#pragma unroll
    for (int nt = 0; nt < 16; nt++) {
        int d = nt * 16 + row;
        float g2 = lng[d], b2 = lnb[d];
#pragma unroll
        for (int r = 0; r < 4; r++)
            out[xb[r] + nt * 16] = (oacc[nt][r] - mu[r]) * rstd[r] * g2 + b2;
    }
}

// ---------------------------------------------------------------------------
extern "C" void kernel_launch(void* const* d_in, const int* in_sizes, int n_in,
                              void* d_out, int out_size, void* d_ws, size_t ws_size,
                              hipStream_t stream) {
    const float* x = (const float*)d_in[0];
    const unsigned char* xmask = (const unsigned char*)d_in[1];
    const int* pos = (const int*)d_in[2];
    const float* pe = (const float*)d_in[3];
    const float* wq = (const float*)d_in[4];
    const float* bq = (const float*)d_in[5];
    const float* wk = (const float*)d_in[6];
    const float* bk = (const float*)d_in[7];
    const float* wv = (const float*)d_in[8];
    const float* bv = (const float*)d_in[9];
    const float* lng = (const float*)d_in[10];
    const float* lnb = (const float*)d_in[11];
    const float* lsg = (const float*)d_in[12];
    float* out = (float*)d_out;

    short* qw = (short*)d_ws;              // 32MB
    short* kw = qw + 16777216;             // 32MB
    short* vtw = kw + 16777216;            // 32MB
    short* wbw = vtw + 16777216;           // 384KB
    float* mbg = (float*)(wbw + 196608);   // 256KB mask bias

    prep_kernel<<<448, 256, 0, stream>>>(wq, wk, wv, xmask, wbw, mbg);
    qkv_mfma_kernel<<<1024, 256, 0, stream>>>(x, pos, pe, wbw, bq, bk, bv,
                                              qw, kw, vtw);
    attn_kernel<<<512, 512, 0, stream>>>(qw, kw, vtw, mbg, x, lsg, lng, lnb, out);
}

// Round 5
// 347.943 us; speedup vs baseline: 1.2720x; 1.2720x over previous
//
#include <hip/hip_runtime.h>

// B=4, T=1024, C=16, D=256, P=4096.  Float tensors fp32; x_mask u8; pos i32.
// ws: q[bc][t][d] bf16 32MB | k[bc][t][d] bf16 32MB | vt[bc][d][t] bf16 32MB
//     | wb[3][256][256] bf16 384KB | mbg[64][1024] f32 256KB

typedef __attribute__((ext_vector_type(8))) short short8_t;
typedef __attribute__((ext_vector_type(4))) short short4_t;
typedef __attribute__((ext_vector_type(8))) float float8_t;
typedef __attribute__((ext_vector_type(4))) float float4_t;
typedef __attribute__((ext_vector_type(2))) float float2_t;

__device__ __forceinline__ float b2f(short s) {
    union { unsigned int u; float f; } x;
    x.u = ((unsigned int)(unsigned short)s) << 16;
    return x.f;
}
__device__ __forceinline__ short f2bt(float f) {   // truncate: ample headroom here
    union { float f; unsigned int u; } x; x.f = f;
    return (short)(x.u >> 16);
}

// async global->LDS, 16B per lane, dest = wave-uniform base + lane*16
__device__ __forceinline__ void stage16(const short* g, short* l) {
    __builtin_amdgcn_global_load_lds(
        (const __attribute__((address_space(1))) unsigned int*)g,
        (__attribute__((address_space(3))) unsigned int*)l, 16, 0, 0);
}

// ---------------------------------------------------------------------------
// Kernel 0: weights fp32->bf16 + mask-bias table. 448 blocks x 256.
// ---------------------------------------------------------------------------
__global__ __launch_bounds__(256) void prep_kernel(
    const float* __restrict__ wq, const float* __restrict__ wk,
    const float* __restrict__ wv, const unsigned char* __restrict__ xmask,
    short* __restrict__ wb, float* __restrict__ mbg)
{
    if (blockIdx.x < 192) {
        int idx = blockIdx.x * 256 + threadIdx.x;
        int mat = idx >> 14, off = idx & 16383;
        const float* src = (mat == 0) ? wq : ((mat == 1) ? wk : wv);
        float4_t v = *(const float4_t*)(src + (long)off * 4);
        short4_t o;
#pragma unroll
        for (int j = 0; j < 4; j++) o[j] = f2bt(v[j]);
        *(short4_t*)(wb + (long)idx * 4) = o;
    } else {
        int idx = (blockIdx.x - 192) * 256 + threadIdx.x;   // 0..65535
        int bc = idx >> 10, t = idx & 1023;
        int b = bc >> 4, c = bc & 15;
        mbg[idx] = xmask[((long)b * 1024 + t) * 16 + c] ? -1e30f : 0.0f;
    }
}

// ---------------------------------------------------------------------------
// Kernel 1: MFMA QKV projection + rotary (unchanged).
// ---------------------------------------------------------------------------
__global__ __launch_bounds__(256) void qkv_mfma_kernel(
    const float* __restrict__ x, const int* __restrict__ pos,
    const float* __restrict__ pe, const short* __restrict__ wb,
    const float* __restrict__ bq, const float* __restrict__ bk,
    const float* __restrict__ bv,
    short* __restrict__ qo, short* __restrict__ ko, short* __restrict__ vt)
{
    __shared__ __align__(16) short xs[64 * 264];
    __shared__ __align__(16) short ys[18432];
    __shared__ int posb[64];

    const int tid = threadIdx.x;
    const int lane = tid & 63;
    const int wid = tid >> 6;
    const int bc = blockIdx.x >> 4;
    const int t0 = (blockIdx.x & 15) * 64;
    const int b = bc >> 4, c = bc & 15;
    const int row = lane & 15, quad = lane >> 4;
    const int odd = lane & 1;
    const int n0 = wid * 64;
    const long kvbase = (long)bc * 262144;

#pragma unroll
    for (int j = 0; j < 8; j++) {
        int idx = tid + j * 256;
        int r = idx >> 5, c8 = idx & 31;
        const float* xp = x + (((long)b * 1024 + t0 + r) * 16 + c) * 256 + c8 * 8;
        float4_t a = *(const float4_t*)xp;
        float4_t d = *(const float4_t*)(xp + 4);
        short8_t o;
        o[0] = f2bt(a.x); o[1] = f2bt(a.y); o[2] = f2bt(a.z); o[3] = f2bt(a.w);
        o[4] = f2bt(d.x); o[5] = f2bt(d.y); o[6] = f2bt(d.z); o[7] = f2bt(d.w);
        *(short8_t*)&xs[r * 264 + c8 * 8] = o;
    }
    if (tid < 64) posb[tid] = pos[((long)b * 1024 + t0 + tid) * 16 + c];
    __syncthreads();

#pragma unroll 1
    for (int mat = 0; mat < 3; mat++) {
        const short* W = wb + mat * 65536;
        float4_t acc[4][4];
#pragma unroll
        for (int mt = 0; mt < 4; mt++)
#pragma unroll
            for (int nt = 0; nt < 4; nt++) acc[mt][nt] = (float4_t){0.f, 0.f, 0.f, 0.f};

        short8_t Ac[4], Bc[4], An[4], Bn[4];
        auto loadA = [&](short8_t* A, int k0) {
#pragma unroll
            for (int mt = 0; mt < 4; mt++)
                A[mt] = *(const short8_t*)&xs[(mt * 16 + row) * 264 + k0 * 32 + quad * 8];
        };
        auto loadB = [&](short8_t* Bf, int k0) {
#pragma unroll
            for (int nt = 0; nt < 4; nt++)
                Bf[nt] = *(const short8_t*)(W + (n0 + nt * 16 + row) * 256 + k0 * 32 + quad * 8);
        };
        loadA(Ac, 0); loadB(Bc, 0);
#pragma unroll
        for (int k0 = 0; k0 < 8; k0++) {
            if (k0 < 7) { loadA(An, k0 + 1); loadB(Bn, k0 + 1); }
#pragma unroll
            for (int mt = 0; mt < 4; mt++)
#pragma unroll
                for (int nt = 0; nt < 4; nt++)
                    acc[mt][nt] = __builtin_amdgcn_mfma_f32_16x16x32_bf16(
                        Ac[mt], Bc[nt], acc[mt][nt], 0, 0, 0);
            if (k0 < 7) {
#pragma unroll
                for (int i = 0; i < 4; i++) { Ac[i] = An[i]; Bc[i] = Bn[i]; }
            }
        }

        const float* bias = (mat == 0) ? bq : ((mat == 1) ? bk : bv);
        float bs[4];
#pragma unroll
        for (int nt = 0; nt < 4; nt++) bs[nt] = bias[n0 + nt * 16 + row];
#pragma unroll
        for (int mt = 0; mt < 4; mt++)
#pragma unroll
            for (int nt = 0; nt < 4; nt++)
#pragma unroll
                for (int r = 0; r < 4; r++) acc[mt][nt][r] += bs[nt];

        if (mat < 2) {
#pragma unroll
            for (int mt = 0; mt < 4; mt++)
#pragma unroll
                for (int r = 0; r < 4; r++) {
                    int p = posb[mt * 16 + quad * 4 + r];
                    const float* pb = pe + (long)p * 256;
#pragma unroll
                    for (int nt = 0; nt < 4; nt++) {
                        int i = (n0 + nt * 16 + row) >> 1;
                        float2_t cs = *(const float2_t*)(pb + i * 2);
                        float v = acc[mt][nt][r];
                        float pr = __shfl_xor(v, 1);
                        acc[mt][nt][r] = v * cs.x + pr * (odd ? cs.y : -cs.y);
                    }
                }
        }

        __syncthreads();
        if (mat < 2) {
#pragma unroll
            for (int mt = 0; mt < 4; mt++)
#pragma unroll
                for (int nt = 0; nt < 4; nt++) {
                    int n = n0 + nt * 16 + row;
#pragma unroll
                    for (int r = 0; r < 4; r++)
                        ys[(mt * 16 + quad * 4 + r) * 264 + n] = f2bt(acc[mt][nt][r]);
                }
            __syncthreads();
            short* dst = ((mat == 0) ? qo : ko) + kvbase + (long)t0 * 256;
#pragma unroll
            for (int j = 0; j < 8; j++) {
                int idx = tid + j * 256;
                int r = idx >> 5, c8 = idx & 31;
                *(short8_t*)(dst + r * 256 + c8 * 8) = *(const short8_t*)&ys[r * 264 + c8 * 8];
            }
        } else {
#pragma unroll
            for (int mt = 0; mt < 4; mt++)
#pragma unroll
                for (int nt = 0; nt < 4; nt++) {
                    int n = n0 + nt * 16 + row;
                    short4_t o4;
#pragma unroll
                    for (int r = 0; r < 4; r++) o4[r] = f2bt(acc[mt][nt][r]);
                    *(short4_t*)&ys[n * 72 + mt * 16 + quad * 4] = o4;
                }
            __syncthreads();
#pragma unroll
            for (int j = 0; j < 8; j++) {
                int idx = tid + j * 256;
                int d = idx >> 3, t8 = idx & 7;
                *(short8_t*)(vt + kvbase + (long)d * 1024 + t0 + t8 * 8) =
                    *(const short8_t*)&ys[d * 72 + t8 * 8];
            }
        }
    }
}

// ---------------------------------------------------------------------------
// Kernel 2: flash attention. 512 thr (8 waves x 16 q-rows = 128 q/block),
// KV-tile 32, QUAD-buffered global_load_lds staging (depth-2 prefetch,
// counted vmcnt + ONE raw s_barrier per iter).  With nb=4, the buffer
// written at iter j ((j+2)%4) differs by 3 (mod 4) from the one the
// slowest wave (max 1 barrier behind) can still read ((j-1)%4) -> the
// end-of-iter barrier is removable: waves skew up to a full iteration,
// overlapping softmax VALU with other waves' MFMA/LDS phases.  setprio(1)
// around MFMA clusters now has genuine role diversity to arbitrate.
// LDS: K 4x16KB | V 4x16KB | PT 8x1.25KB | mask 4KB = 142KB -> 1 block/CU.
// Registers: same as verified r2 (96 VGPR, no spill).
// ---------------------------------------------------------------------------
__global__ __launch_bounds__(512, 2) void attn_kernel(
    const short* __restrict__ qg, const short* __restrict__ kg,
    const short* __restrict__ vt, const float* __restrict__ mbg,
    const float* __restrict__ x,
    const float* __restrict__ lsg, const float* __restrict__ lng,
    const float* __restrict__ lnb, float* __restrict__ out)
{
    __shared__ __align__(16) short lds[72704];   // 145408 B
    // shorts: Ks[buf<4] @ buf*8192 (row r*256, 16B slot s holds gcol-slot s^(r&7))
    //         Vs[buf<4] @ 32768+buf*8192 (row d*32, 4 slots, slot s = gslot^((d>>1)&3))
    //         PT[wave]  @ 65536+wid*640  (32 k-rows x stride 20 shorts)
    //         mbs f32   @ 70656 (1024 floats)

    const int tid = threadIdx.x;
    const int lane = tid & 63;
    const int wid = tid >> 6;
    // 512 blocks, 8 XCDs: chunked swizzle -> 64 consecutive bids per XCD
    const int bid = (blockIdx.x & 7) * 64 + (blockIdx.x >> 3);
    const int bc = bid >> 3;
    const int tq0 = (bid & 7) * 128;
    const int b = bc >> 4, c = bc & 15;
    const long kvbase = (long)bc * 262144;
    const int bcq = bc * 1024;
    const int row = lane & 15, quad = lane >> 4;
    float* mbsf = (float*)&lds[70656];

    auto stage = [&](int j, int buf) {
#pragma unroll
        for (int i = 0; i < 2; i++) {            // K tile: 32 rows x 512B
            int rp = (wid * 2 + i) * 2;
            int r = rp + (lane >> 5);
            int slot = lane & 31;
            const short* g = kg + kvbase + (long)(j * 32 + r) * 256 +
                             ((slot ^ (r & 7)) << 3);
            stage16(g, &lds[buf * 8192 + rp * 256]);
        }
#pragma unroll
        for (int i = 0; i < 2; i++) {            // V tile: 256 d-rows x 64B
            int db = (wid * 2 + i) * 16;
            int d = db + (lane >> 2);
            int slot = lane & 3;
            const short* g = vt + kvbase + (long)d * 1024 + j * 32 +
                             (((slot ^ ((d >> 1) & 3))) << 3);
            stage16(g, &lds[32768 + buf * 8192 + db * 32]);
        }
    };

    // ---- prologue: stage tiles 0,1; mask row -> LDS; Q frags -> regs ----
    stage(0, 0);
    stage(1, 1);
#pragma unroll
    for (int i = tid; i < 1024; i += 512) mbsf[i] = mbg[bcq + i];
    short8_t aq[8];
#pragma unroll
    for (int f = 0; f < 8; f++)
        aq[f] = *(const short8_t*)(qg + kvbase +
            (long)(tq0 + wid * 16 + row) * 256 + f * 32 + quad * 8);

    float4_t oacc[16];
#pragma unroll
    for (int nt = 0; nt < 16; nt++) oacc[nt] = (float4_t){0.f, 0.f, 0.f, 0.f};
    float m[4], lsum[4];
#pragma unroll
    for (int r = 0; r < 4; r++) { m[r] = -__builtin_inff(); lsum[r] = 0.f; }

    const float scale = 0.0625f;
    const int ptw = 65536 + wid * 640 + row * 20 + quad * 4;   // PT write (k=row(+16))
    const int prd = 65536 + wid * 640 + quad * 160 + row;      // PT read (k=quad*8+jj)

    asm volatile("s_waitcnt lgkmcnt(0)" ::: "memory");   // mbs ds_writes done

#pragma unroll 1
    for (int j = 0; j < 32; j++) {
        if (j < 30) {
            stage(j + 2, (j + 2) & 3);
            asm volatile("s_waitcnt vmcnt(8)" ::: "memory");  // tile j landed
        } else if (j == 30) {
            asm volatile("s_waitcnt vmcnt(4)" ::: "memory");
        } else {
            asm volatile("s_waitcnt vmcnt(0)" ::: "memory");
        }
        __builtin_amdgcn_s_barrier();        // tile j staged for all waves
                                             // (only barrier in the loop)

        const short* Kb = &lds[(j & 3) * 8192];
        const short* Vb = &lds[32768 + (j & 3) * 8192];

        // S = Q K^T  (two 16-col tiles)
        float4_t s0 = {0.f, 0.f, 0.f, 0.f}, s1 = {0.f, 0.f, 0.f, 0.f};
        __builtin_amdgcn_s_setprio(1);
#pragma unroll
        for (int f = 0; f < 8; f++) {
            short8_t k0 = *(const short8_t*)&Kb[row * 256 + (((f * 4 + quad) ^ (row & 7)) << 3)];
            short8_t k1 = *(const short8_t*)&Kb[(16 + row) * 256 + (((f * 4 + quad) ^ ((16 + row) & 7)) << 3)];
            s0 = __builtin_amdgcn_mfma_f32_16x16x32_bf16(aq[f], k0, s0, 0, 0, 0);
            s1 = __builtin_amdgcn_mfma_f32_16x16x32_bf16(aq[f], k1, s1, 0, 0, 0);
        }
        __builtin_amdgcn_s_setprio(0);
        float mb0 = mbsf[j * 32 + row], mb1 = mbsf[j * 32 + 16 + row];
        float sv[2][4], tm[4];
#pragma unroll
        for (int r = 0; r < 4; r++) {
            sv[0][r] = s0[r] * scale + mb0;
            sv[1][r] = s1[r] * scale + mb1;
            tm[r] = fmaxf(sv[0][r], sv[1][r]);
        }
#pragma unroll
        for (int r = 0; r < 4; r++)
#pragma unroll
            for (int o = 1; o < 16; o <<= 1) tm[r] = fmaxf(tm[r], __shfl_xor(tm[r], o));
        float g = fmaxf(fmaxf(tm[0] - m[0], tm[1] - m[1]),
                        fmaxf(tm[2] - m[2], tm[3] - m[3]));
        if (!__all(g <= 8.f)) {                          // rescale (rare: defer-max)
#pragma unroll
            for (int r = 0; r < 4; r++) {
                float nm = fmaxf(m[r], tm[r]);
                float fac = __expf(m[r] - nm);
                lsum[r] *= fac; m[r] = nm;
#pragma unroll
                for (int nt = 0; nt < 16; nt++) oacc[nt][r] *= fac;
            }
        }
        short4_t p4[2];
#pragma unroll
        for (int h = 0; h < 2; h++)
#pragma unroll
            for (int r = 0; r < 4; r++) {
                float p = __expf(sv[h][r] - m[r]);
                lsum[r] += p;
                p4[h][r] = f2bt(p);
            }
        *(short4_t*)&lds[ptw] = p4[0];
        *(short4_t*)&lds[ptw + 320] = p4[1];
        short8_t pa;
#pragma unroll
        for (int jj = 0; jj < 8; jj++) pa[jj] = lds[prd + jj * 20];

        // O += P V
        __builtin_amdgcn_s_setprio(1);
#pragma unroll
        for (int nt = 0; nt < 16; nt++) {
            int d = nt * 16 + row;
            short8_t vbf = *(const short8_t*)&Vb[d * 32 + ((quad ^ ((d >> 1) & 3)) << 3)];
            oacc[nt] = __builtin_amdgcn_mfma_f32_16x16x32_bf16(pa, vbf, oacc[nt], 0, 0, 0);
        }
        __builtin_amdgcn_s_setprio(0);
        // no end-of-iter barrier: nb=4 makes stage(j+3)'s target buffer
        // disjoint from any buffer a (max-1-barrier-behind) wave still reads
    }

    // ---- epilogue: finish softmax norm; y = x + ls*o; LayerNorm; store ----
    float inv[4];
#pragma unroll
    for (int r = 0; r < 4; r++) {
        float s = lsum[r];
#pragma unroll
        for (int o = 1; o < 16; o <<= 1) s += __shfl_xor(s, o);
        int qi = tq0 + wid * 16 + quad * 4 + r;
        inv[r] = (mbsf[qi] != 0.f) ? 0.f : (1.f / s);
    }
    long xb[4];
#pragma unroll
    for (int r = 0; r < 4; r++)
        xb[r] = (((long)b * 1024 + tq0 + wid * 16 + quad * 4 + r) * 16 + c) * 256 + row;

    float s1r[4] = {0.f, 0.f, 0.f, 0.f}, s2r[4] = {0.f, 0.f, 0.f, 0.f};
#pragma unroll
    for (int nt = 0; nt < 16; nt++) {
        int d = nt * 16 + row;
        float lg = lsg[d];
#pragma unroll
        for (int r = 0; r < 4; r++) {
            float yy = x[xb[r] + nt * 16] + lg * (oacc[nt][r] * inv[r]);
            oacc[nt][r] = yy;
            s1r[r] += yy; s2r[r] += yy * yy;
        }
    }
    float mu[4], rstd[4];
#pragma unroll
    for (int r = 0; r < 4; r++) {
#pragma unroll
        for (int o = 1; o < 16; o <<= 1) {
            s1r[r] += __shfl_xor(s1r[r], o);
            s2r[r] += __shfl_xor(s2r[r], o);
        }
        mu[r] = s1r[r] * (1.f / 256.f);
        float var = s2r[r] * (1.f / 256.f) - mu[r] * mu[r];
        rstd[r] = rsqrtf(var + 1e-5f);
    }
#pragma unroll
    for (int nt = 0; nt < 16; nt++) {
        int d = nt * 16 + row;
        float g2 = lng[d], b2 = lnb[d];
#pragma unroll
        for (int r = 0; r < 4; r++)
            out[xb[r] + nt * 16] = (oacc[nt][r] - mu[r]) * rstd[r] * g2 + b2;
    }
}

// ---------------------------------------------------------------------------
extern "C" void kernel_launch(void* const* d_in, const int* in_sizes, int n_in,
                              void* d_out, int out_size, void* d_ws, size_t ws_size,
                              hipStream_t stream) {
    const float* x = (const float*)d_in[0];
    const unsigned char* xmask = (const unsigned char*)d_in[1];
    const int* pos = (const int*)d_in[2];
    const float* pe = (const float*)d_in[3];
    const float* wq = (const float*)d_in[4];
    const float* bq = (const float*)d_in[5];
    const float* wk = (const float*)d_in[6];
    const float* bk = (const float*)d_in[7];
    const float* wv = (const float*)d_in[8];
    const float* bv = (const float*)d_in[9];
    const float* lng = (const float*)d_in[10];
    const float* lnb = (const float*)d_in[11];
    const float* lsg = (const float*)d_in[12];
    float* out = (float*)d_out;

    short* qw = (short*)d_ws;              // 32MB
    short* kw = qw + 16777216;             // 32MB
    short* vtw = kw + 16777216;            // 32MB
    short* wbw = vtw + 16777216;           // 384KB
    float* mbg = (float*)(wbw + 196608);   // 256KB mask bias

    prep_kernel<<<448, 256, 0, stream>>>(wq, wk, wv, xmask, wbw, mbg);
    qkv_mfma_kernel<<<1024, 256, 0, stream>>>(x, pos, pe, wbw, bq, bk, bv,
                                              qw, kw, vtw);
    attn_kernel<<<512, 512, 0, stream>>>(qw, kw, vtw, mbg, x, lsg, lng, lnb, out);
}